// Round 4
// baseline (2570.650 us; speedup 1.0000x reference)
//
#include <hip/hip_runtime.h>
#include <math.h>

typedef __bf16 bf16_t;
typedef __bf16 bf16x8 __attribute__((ext_vector_type(8)));
typedef float f32x4 __attribute__((ext_vector_type(4)));

#define H    8
#define SD   17
#define HD   240
#define KIN  257      // input dim (f32 rows)
#define KQP  288      // padded K for projections
#define SCOL 256      // s-block width (8 heads x 32)
#define HCOL 1920     // h-block width (8 heads x 240)
#define DTOT 2176     // SCOL + HCOL
#define NTOT 30000
#define CH   7500
#define CHP  7680     // CH padded to 128
#define NCHUNK 4
#define KSPLIT 8

#define BK   32
#define LDSP 40       // LDS row stride in halves (32 + 8 pad)

__device__ __forceinline__ float phi_elu1(float x) {
    return x > 0.f ? x + 1.f : __expf(x);
}

struct GemmP {
    const void* A; long lda; long aHead; int KA;   // A: bf16 (or f32 if CASTA)
    const bf16_t* B; long ldb; long bHead;         // B: bf16, rows padded+zeroed to >= ceil32(K)
    float* Cf; bf16_t* Cb; long ldc; long cHead; int atomicC;
    const float* rs; int rsStride; long rsHead; float eps;
    int M, N, K, nSplit;
};

// C[m,n] = sum_k A[m,k]*B[n,k], bf16 MFMA, f32 acc.
template<int TBM, int TBN, bool CASTA>
__global__ void __launch_bounds__(256)
k_mfma_nt(GemmP p)
{
    constexpr int FI = TBM / 32;
    constexpr int FJ = TBN / 32;
    __shared__ bf16_t As[TBM * LDSP];
    __shared__ bf16_t Bs[TBN * LDSP];
    const int t  = threadIdx.x;
    const int z  = blockIdx.z;
    const int h  = z / p.nSplit;
    const int sp = z % p.nSplit;
    const int kWin = p.K / p.nSplit;
    const int k0   = sp * kWin;
    const int m0 = blockIdx.x * TBM;
    const int n0 = blockIdx.y * TBN;
    const bf16_t* B = p.B + (long)h * p.bHead;

    const int lr = t >> 2;
    const int lc = t & 3;
    const int wid  = t >> 6;
    const int lane = t & 63;
    const int wm = (wid >> 1) * (TBM / 2);
    const int wn = (wid & 1) * (TBN / 2);
    const int fr = lane & 15;
    const int fq = lane >> 4;

    f32x4 acc[FI][FJ] = {};

    for (int kb = k0; kb < k0 + kWin; kb += BK) {
        if (CASTA) {
            const float* Af = (const float*)p.A + (long)h * p.aHead;
            const int kpos = t & 31, rowg = t >> 5;
#pragma unroll
            for (int it = 0; it < TBM / 8; ++it) {
                const int r = it * 8 + rowg;
                const int gm = m0 + r, gk = kb + kpos;
                float v = (gm < p.M && gk < p.KA) ? Af[(long)gm * p.lda + gk] : 0.f;
                As[r * LDSP + kpos] = (bf16_t)v;
            }
        } else {
            const bf16_t* Ab = (const bf16_t*)p.A + (long)h * p.aHead;
#pragma unroll
            for (int it = 0; it < TBM / 64; ++it) {
                const int r = lr + it * 64;
                const int gm = m0 + r, gk = kb + lc * 8;
                bf16x8 va = {};
                if (gm < p.M) {
                    if (gk + 8 <= p.KA) va = *(const bf16x8*)(Ab + (long)gm * p.lda + gk);
                    else {
#pragma unroll
                        for (int e = 0; e < 8; ++e)
                            if (gk + e < p.KA) va[e] = Ab[(long)gm * p.lda + gk + e];
                    }
                }
                *(bf16x8*)(As + r * LDSP + lc * 8) = va;
            }
        }
#pragma unroll
        for (int it = 0; it < TBN / 64; ++it) {
            const int r = lr + it * 64;
            const int gn = n0 + r, gk = kb + lc * 8;
            bf16x8 vb = {};
            if (gn < p.N) vb = *(const bf16x8*)(B + (long)gn * p.ldb + gk);
            *(bf16x8*)(Bs + r * LDSP + lc * 8) = vb;
        }
        __syncthreads();
        bf16x8 af[FI], bf[FJ];
#pragma unroll
        for (int i = 0; i < FI; ++i)
            af[i] = *(const bf16x8*)(As + (wm + i * 16 + fr) * LDSP + fq * 8);
#pragma unroll
        for (int j = 0; j < FJ; ++j)
            bf[j] = *(const bf16x8*)(Bs + (wn + j * 16 + fr) * LDSP + fq * 8);
#pragma unroll
        for (int i = 0; i < FI; ++i)
#pragma unroll
            for (int j = 0; j < FJ; ++j)
                acc[i][j] = __builtin_amdgcn_mfma_f32_16x16x32_bf16(af[i], bf[j], acc[i][j], 0, 0, 0);
        __syncthreads();
    }

    float*  Cf = p.Cf ? p.Cf + (long)h * p.cHead : (float*)0;
    bf16_t* Cb = p.Cb ? p.Cb + (long)h * p.cHead : (bf16_t*)0;
    const float* rs = p.rs ? p.rs + (long)h * p.rsHead : (const float*)0;
#pragma unroll
    for (int i = 0; i < FI; ++i) {
#pragma unroll
        for (int r = 0; r < 4; ++r) {
            const int m = m0 + wm + i * 16 + fq * 4 + r;
            if (m >= p.M) continue;
            float sc = 1.f;
            if (rs) sc = 1.f / (rs[(long)m * p.rsStride] + p.eps);
#pragma unroll
            for (int j = 0; j < FJ; ++j) {
                const int n = n0 + wn + j * 16 + fr;
                if (n >= p.N) continue;
                const float v = acc[i][j][r] * sc;
                const long idx = (long)m * p.ldc + n;
                if (p.atomicC)      atomicAdd(&Cf[idx], v);
                else if (Cf)        Cf[idx] = v;
                else                Cb[idx] = (bf16_t)v;
            }
        }
    }
}

// Wq/Wk/Wv [H][257][257] -> split-padded [2176][288]
__global__ void k_prep_proj(const float* __restrict__ W, bf16_t* __restrict__ dst)
{
    long i = (long)blockIdx.x * 256 + threadIdx.x;
    if (i >= (long)DTOT * KQP) return;
    int r = (int)(i / KQP), k = (int)(i % KQP);
    float v = 0.f;
    if (r < SCOL) {
        int h = r >> 5, j = r & 31;
        if (j < SD && k < KIN) v = W[((long)h * 257 + j) * 257 + k];
    } else {
        int rr = r - SCOL;
        int h = rr / HD, j = rr % HD;
        if (k < KIN) v = W[((long)h * 257 + SD + j) * 257 + k];
    }
    dst[i] = (bf16_t)v;
}

// Ws [17][136], Wh [240][1920] -> block-diag Wout [320][2176]
__global__ void k_prep_wout(const float* __restrict__ Ws, const float* __restrict__ Wh,
                            bf16_t* __restrict__ dst)
{
    long i = (long)blockIdx.x * 256 + threadIdx.x;
    if (i >= 320L * DTOT) return;
    int o = (int)(i / DTOT), c = (int)(i % DTOT);
    float v = 0.f;
    if (o < SD) {
        if (c < SCOL) {
            int h = c >> 5, jj = c & 31;
            if (jj < SD) v = Ws[(long)o * (H * SD) + h * SD + jj];
        }
    } else if (o < 257) {
        if (c >= SCOL) v = Wh[(long)(o - SD) * HCOL + (c - SCOL)];
    }
    dst[i] = (bf16_t)v;
}

// in-place post for fused KV: norm s-parts (k:+phi, v:scale only), phi on k h-part
__global__ void __launch_bounds__(256)
k_post_kv(bf16_t* __restrict__ Ykv, int rows)
{
    const int wid  = blockIdx.x * 4 + (threadIdx.x >> 6);
    const int lane = threadIdx.x & 63;
    const int n = wid >> 3, h = wid & 7;
    if (n >= rows) return;
    bf16_t* row = Ykv + (long)n * (2 * DTOT);
    float kv = 0.f, vv = 0.f;
    if (lane < SD) {
        kv = (float)row[h * 32 + lane];
        vv = (float)row[DTOT + h * 32 + lane];
    }
    float sk = kv * kv, sv = vv * vv;
#pragma unroll
    for (int off = 32; off > 0; off >>= 1) {
        sk += __shfl_down(sk, off);
        sv += __shfl_down(sv, off);
    }
    sk = __shfl(sk, 0); sv = __shfl(sv, 0);
    const float ik = 1.f / (sqrtf(sk) + 1e-8f);
    const float iv = 1.f / (sqrtf(sv) + 1e-8f);
    if (lane < 32) {
        row[h * 32 + lane]        = (bf16_t)((lane < SD) ? phi_elu1(kv * ik) : 0.f);
        row[DTOT + h * 32 + lane] = (bf16_t)((lane < SD) ? vv * iv : 0.f);
    }
    for (int o = lane; o < HD; o += 64) {
        bf16_t* pk = row + SCOL + h * HD + o;
        *pk = (bf16_t)phi_elu1((float)*pk);
    }
}

// in-place post for Q + den via ksum
__global__ void __launch_bounds__(256)
k_post_q(bf16_t* __restrict__ Yq, const float* __restrict__ ksum,
         float* __restrict__ den_s, float* __restrict__ den_h, int rows)
{
    const int wid  = blockIdx.x * 4 + (threadIdx.x >> 6);
    const int lane = threadIdx.x & 63;
    const int n = wid >> 3, h = wid & 7;
    if (n >= rows) return;
    bf16_t* row = Yq + (long)n * DTOT;
    float qv = (lane < SD) ? (float)row[h * 32 + lane] : 0.f;
    float sq = qv * qv;
#pragma unroll
    for (int off = 32; off > 0; off >>= 1) sq += __shfl_down(sq, off);
    sq = __shfl(sq, 0);
    const float iq = 1.f / (sqrtf(sq) + 1e-8f);
    float ds = 0.f, dh = 0.f;
    if (lane < 32) {
        float pv = 0.f;
        if (lane < SD) {
            pv = phi_elu1(qv * iq);
            ds = pv * ksum[h * 32 + lane];
        }
        row[h * 32 + lane] = (bf16_t)pv;
    }
    for (int o = lane; o < HD; o += 64) {
        bf16_t* pq = row + SCOL + h * HD + o;
        float pv = phi_elu1((float)*pq);
        *pq = (bf16_t)pv;
        dh += pv * ksum[SCOL + h * HD + o];
    }
#pragma unroll
    for (int off = 32; off > 0; off >>= 1) {
        ds += __shfl_down(ds, off);
        dh += __shfl_down(dh, off);
    }
    if (lane == 0) { den_s[n * H + h] = ds; den_h[n * H + h] = dh; }
}

// column sums (atomic across row splits); X row-major with lda
__global__ void k_colsum(const bf16_t* __restrict__ X, long lda, float* __restrict__ out,
                         int rows, int W)
{
    int col = blockIdx.x * 256 + threadIdx.x;
    if (col >= W) return;
    int per = (rows + gridDim.y - 1) / gridDim.y;
    int r0 = blockIdx.y * per;
    int r1 = r0 + per; if (r1 > rows) r1 = rows;
    float s = 0.f;
    for (int r = r0; r < r1; ++r) s += (float)X[(long)r * lda + col];
    atomicAdd(&out[col], s);
}

// transpose X[R][.] cols [off, off+ncols) -> T[col][CHP], zero-fill rows >= R
__global__ void __launch_bounds__(256)
k_transpose(const bf16_t* __restrict__ X, long lda, long off,
            bf16_t* __restrict__ T, int R)
{
    const int t = threadIdx.x;
    const int c = t & 63;
    const int rchunk = t >> 6;
    const int r0 = blockIdx.x * 128;
    const int gc = blockIdx.y * 64 + c;
    bf16x8 w[4];
#pragma unroll
    for (int j = 0; j < 32; ++j) {
        const int gr = r0 + rchunk * 32 + j;
        float v = 0.f;
        if (gr < R) v = (float)X[(long)gr * lda + off + gc];
        w[j >> 3][j & 7] = (bf16_t)v;
    }
    bf16_t* dst = T + (long)gc * CHP + r0 + rchunk * 32;
#pragma unroll
    for (int q = 0; q < 4; ++q)
        *(bf16x8*)(dst + q * 8) = w[q];
}

// f32 -> bf16
__global__ void k_castf(const float* __restrict__ in, bf16_t* __restrict__ out, long n)
{
    long i = (long)blockIdx.x * 256 + threadIdx.x;
    if (i < n) out[i] = (bf16_t)in[i];
}

// final epilogue: pre[n][257] (s=0..16 raw a, h=17..256 raw b) -> out[n][257]
__global__ void __launch_bounds__(256)
k_finalize(const float* __restrict__ pre, float* __restrict__ outp, int rows)
{
    int n    = blockIdx.x * 4 + (threadIdx.x >> 6);
    int lane = threadIdx.x & 63;
    if (n >= rows) return;
    const float* rp = pre + (long)n * 257;
    float* op = outp + (long)n * 257;
    float sv = (lane < SD) ? rp[lane] : 0.f;
    float ssq = sv * sv;
    float hv[4];
    float hsq = 0.f;
#pragma unroll
    for (int i = 0; i < 4; ++i) {
        int o = lane + 64 * i;
        hv[i] = (o < HD) ? rp[SD + o] : 0.f;
        hsq += hv[i] * hv[i];
    }
#pragma unroll
    for (int off = 32; off > 0; off >>= 1) {
        ssq += __shfl_down(ssq, off);
        hsq += __shfl_down(hsq, off);
    }
    ssq = __shfl(ssq, 0); hsq = __shfl(hsq, 0);
    float an_raw = sqrtf(ssq);
    float bn_raw = sqrtf(hsq);
    float an = an_raw + 1e-8f;
    float bn = bn_raw + 1e-8f;
    bool ma = an > 1e6f;
    bool mb = bn > 1e6f;
    float an_c = fminf(an, 1e6f);
    float bn_c = fminf(bn, 1e6f);
    float na = ma ? (an_raw / an_c) : an_raw;
    na = fmaxf(na, 1e-12f);
    float inv_s = (ma ? (1.f / an_c) : 1.f) / na;
    float bt = sqrtf(bn_c * bn_c + 1.0f);
    float nb = fmaxf(bn_raw / bn_c, 1e-12f);
    float scale_b = 1e6f / (bn_c * nb);
    if (lane < SD) op[lane] = bt * (sv * inv_s);
#pragma unroll
    for (int i = 0; i < 4; ++i) {
        int o = lane + 64 * i;
        if (o < HD) op[SD + o] = mb ? hv[i] * scale_b : hv[i];
    }
}

static inline long alup(long b) { return (b + 255) & ~255L; }

extern "C" void kernel_launch(void* const* d_in, const int* in_sizes, int n_in,
                              void* d_out, int out_size, void* d_ws, size_t ws_size,
                              hipStream_t stream)
{
    const float* query  = (const float*)d_in[0];
    const float* source = (const float*)d_in[1];
    const float* Wq     = (const float*)d_in[2];
    const float* Wk     = (const float*)d_in[3];
    const float* Wv     = (const float*)d_in[4];
    const float* Ws     = (const float*)d_in[5];
    const float* Wh     = (const float*)d_in[6];
    float* out = (float*)d_out;

    // ---- workspace layout (~149 MB; round-3 counters prove ws >= ~205 MB) ----
    char* p = (char*)d_ws;
    auto alloc = [&](long b) { char* r = p; p += alup(b); return r; };
    bf16_t* Wkvb = (bf16_t*)alloc(2L * DTOT * KQP * 2);     // [4352][288]
    bf16_t* Wqb  = (bf16_t*)alloc((long)DTOT * KQP * 2);    // [2176][288]
    bf16_t* Wout = (bf16_t*)alloc(320L * DTOT * 2);         // [320][2176]
    bf16_t* Ykv  = (bf16_t*)alloc((long)CH * 2 * DTOT * 2); // [7500][4352]
    // union: source phase {Tk,Tv}; query phase {Yq,num}
    char* ubase = alloc(2L * DTOT * CHP * 2);
    bf16_t* Tk  = (bf16_t*)ubase;                           // [2176][7680]
    bf16_t* Tv  = Tk + (long)DTOT * CHP;
    bf16_t* Yq  = (bf16_t*)ubase;                           // [7500][2176]
    bf16_t* num = Tv;                                       // [7500][2176]
    float*  ktvTh  = (float*) alloc(8L * HD * 256 * 4);     // [8][240][256]
    float*  ktvTs  = (float*) alloc(8L * 32 * 32 * 4);      // [8][32][32]
    bf16_t* ktvThb = (bf16_t*)alloc(8L * HD * 256 * 2);
    bf16_t* ktvTsb = (bf16_t*)alloc(8L * 32 * 32 * 2);
    float*  ksum   = (float*) alloc((long)DTOT * 4);
    float*  den_s  = (float*) alloc((long)CH * H * 4);
    float*  den_h  = (float*) alloc((long)CH * H * 4);
    float*  opre   = (float*) alloc((long)CH * 257 * 4);

    // zero atomic accumulators (ktvTh..ksum contiguous)
    (void)hipMemsetAsync(ktvTh, 0, (char*)(ksum + DTOT) - (char*)ktvTh, stream);

    // ---- weight prep ----
    k_prep_proj<<<(unsigned)(((long)DTOT * KQP + 255) / 256), 256, 0, stream>>>(Wk, Wkvb);
    k_prep_proj<<<(unsigned)(((long)DTOT * KQP + 255) / 256), 256, 0, stream>>>(Wv, Wkvb + (long)DTOT * KQP);
    k_prep_proj<<<(unsigned)(((long)DTOT * KQP + 255) / 256), 256, 0, stream>>>(Wq, Wqb);
    k_prep_wout<<<(unsigned)((320L * DTOT + 255) / 256), 256, 0, stream>>>(Ws, Wh, Wout);

    GemmP g;
    const unsigned gM = (CH + 127) / 128;

    // ---------------- source phase ----------------
    for (int c = 0; c < NCHUNK; ++c) {
        const float* src = source + (long)c * CH * KIN;
        // Ykv = src @ Wkvb^T  (cast-in-staging, N=4352)
        g = { src, KIN, 0, KIN,  Wkvb, KQP, 0,  0, Ykv, 2 * DTOT, 0, 0,
              0, 0, 0, 0.f,  CH, 2 * DTOT, KQP, 1 };
        k_mfma_nt<128, 128, true><<<dim3(gM, (2 * DTOT) / 128, 1), 256, 0, stream>>>(g);
        k_post_kv<<<(CH * H) / 4, 256, 0, stream>>>(Ykv, CH);
        k_colsum<<<dim3((DTOT + 255) / 256, 30), 256, 0, stream>>>(Ykv, 2 * DTOT, ksum, CH, DTOT);
        // transposes: phiK (cols 0..2175) and V (cols 2176..4351)
        k_transpose<<<dim3(CHP / 128, DTOT / 64), 256, 0, stream>>>(Ykv, 2 * DTOT, 0, Tk, CH);
        k_transpose<<<dim3(CHP / 128, DTOT / 64), 256, 0, stream>>>(Ykv, 2 * DTOT, DTOT, Tv, CH);
        // ktvT_h[h][v][m] += sum_n Tv_h[v][n] * Tk_h[m][n]   (split-K atomic)
        g = { Tv + (long)SCOL * CHP, CHP, (long)HD * CHP, CHP,
              Tk + (long)SCOL * CHP, CHP, (long)HD * CHP,
              ktvTh, 0, 256, (long)HD * 256, 1,
              0, 0, 0, 0.f,  HD, HD, CHP, KSPLIT };
        k_mfma_nt<128, 128, false><<<dim3(2, 2, H * KSPLIT), 256, 0, stream>>>(g);
        g = { Tv, CHP, 32L * CHP, CHP,  Tk, CHP, 32L * CHP,
              ktvTs, 0, 32, 32L * 32, 1,
              0, 0, 0, 0.f,  32, 32, CHP, KSPLIT };
        k_mfma_nt<64, 64, false><<<dim3(1, 1, H * KSPLIT), 256, 0, stream>>>(g);
    }
    k_castf<<<(unsigned)((8L * (HD * 256 + 32 * 32) + 255) / 256), 256, 0, stream>>>(
        ktvTh, ktvThb, 8L * (HD * 256 + 32 * 32));

    // ---------------- query phase ----------------
    for (int c = 0; c < NCHUNK; ++c) {
        const float* qsrc = query + (long)c * CH * KIN;
        float* orow = out + (long)c * CH * 257;
        // Yq = qsrc @ Wqb^T
        g = { qsrc, KIN, 0, KIN,  Wqb, KQP, 0,  0, Yq, DTOT, 0, 0,
              0, 0, 0, 0.f,  CH, DTOT, KQP, 1 };
        k_mfma_nt<128, 128, true><<<dim3(gM, DTOT / 128, 1), 256, 0, stream>>>(g);
        k_post_q<<<(CH * H) / 4, 256, 0, stream>>>(Yq, ksum, den_s, den_h, CH);
        // num_h: per head, A=phiQ_h [CH][240] (lda DTOT), B=ktvTh_b [240][256]
        g = { Yq + SCOL, DTOT, HD, HD,  ktvThb, 256, (long)HD * 256,
              0, num + SCOL, DTOT, HD, 0,
              den_h, H, 1, 1e-8f,  CH, HD, HD, 1 };
        k_mfma_nt<128, 128, false><<<dim3(gM, 2, H), 256, 0, stream>>>(g);
        // num_s: per head, A=phiQ_s [CH][32], B=ktvTs_b [32][32]
        g = { Yq, DTOT, 32, 32,  ktvTsb, 32, 32L * 32,
              0, num, DTOT, 32, 0,
              den_s, H, 1, 1e-6f,  CH, 32, 32, 1 };
        k_mfma_nt<64, 64, false><<<dim3((CH + 63) / 64, 1, H), 256, 0, stream>>>(g);
        // opre = num @ Wout^T  (N=257, K=2176)
        g = { num, DTOT, 0, DTOT,  Wout, DTOT, 0,  opre, 0, 257, 0, 0,
              0, 0, 0, 0.f,  CH, 257, DTOT, 1 };
        k_mfma_nt<64, 64, false><<<dim3((CH + 63) / 64, 5, 1), 256, 0, stream>>>(g);
        k_finalize<<<(CH + 3) / 4, 256, 0, stream>>>(opre, orow, CH);
    }
}

// Round 5
// 1703.576 us; speedup vs baseline: 1.5090x; 1.5090x over previous
//
#include <hip/hip_runtime.h>
#include <math.h>

typedef __bf16 bf16_t;
typedef __bf16 bf16x8 __attribute__((ext_vector_type(8)));
typedef float f32x4 __attribute__((ext_vector_type(4)));

#define H    8
#define SD   17
#define HD   240
#define KIN  257
#define KQP  288      // padded K for projections
#define SCOL 256      // s-block width (8 x 32)
#define DTOT 2176     // 256 + 1920
#define NTOT 30000
#define CHS  6000     // source chunk
#define NCS  5
#define CHPS 6144     // CHS padded to 128
#define CHQ  7500     // query chunk
#define NCQ  4
#define KSPLIT 16

#define BK   32
#define LDSP 40       // LDS row stride in halves (32 + 8 pad)

__device__ __forceinline__ float phi_elu1(float x) {
    return x > 0.f ? x + 1.f : __expf(x);
}

struct GemmP {
    const bf16_t* A; long lda; long aHead;
    const bf16_t* B; long ldb; long bHead;
    float* Cf; bf16_t* Cb; long ldc; long cHead; int atomicC;
    int M, N, K, nSplit;
};

// C[m,n] = sum_k A[m,k]*B[n,k]; bf16 MFMA, f32 acc. K (per split) mult of 32,
// operand rows padded/zeroed so bf16x8 loads at any gk < K are safe.
template<int TBM, int TBN>
__global__ void __launch_bounds__(256)
k_mfma_nt(GemmP p)
{
    constexpr int FI = TBM / 32;
    constexpr int FJ = TBN / 32;
    __shared__ bf16_t As[TBM * LDSP];
    __shared__ bf16_t Bs[TBN * LDSP];
    const int t  = threadIdx.x;
    const int z  = blockIdx.z;
    const int h  = z / p.nSplit;
    const int sp = z % p.nSplit;
    const int kWin = p.K / p.nSplit;
    const int k0   = sp * kWin;
    const int m0 = blockIdx.x * TBM;
    const int n0 = blockIdx.y * TBN;
    const bf16_t* A = p.A + (long)h * p.aHead;
    const bf16_t* B = p.B + (long)h * p.bHead;

    const int lr = t >> 2;
    const int lc = t & 3;
    const int wid  = t >> 6;
    const int lane = t & 63;
    const int wm = (wid >> 1) * (TBM / 2);
    const int wn = (wid & 1) * (TBN / 2);
    const int fr = lane & 15;
    const int fq = lane >> 4;

    f32x4 acc[FI][FJ] = {};

    for (int kb = k0; kb < k0 + kWin; kb += BK) {
        const int gk = kb + lc * 8;
#pragma unroll
        for (int it = 0; it < TBM / 64; ++it) {
            const int r = lr + it * 64;
            const int gm = m0 + r;
            bf16x8 va = {};
            if (gm < p.M) va = *(const bf16x8*)(A + (long)gm * p.lda + gk);
            *(bf16x8*)(As + r * LDSP + lc * 8) = va;
        }
#pragma unroll
        for (int it = 0; it < TBN / 64; ++it) {
            const int r = lr + it * 64;
            const int gn = n0 + r;
            bf16x8 vb = {};
            if (gn < p.N) vb = *(const bf16x8*)(B + (long)gn * p.ldb + gk);
            *(bf16x8*)(Bs + r * LDSP + lc * 8) = vb;
        }
        __syncthreads();
        bf16x8 af[FI], bf[FJ];
#pragma unroll
        for (int i = 0; i < FI; ++i)
            af[i] = *(const bf16x8*)(As + (wm + i * 16 + fr) * LDSP + fq * 8);
#pragma unroll
        for (int j = 0; j < FJ; ++j)
            bf[j] = *(const bf16x8*)(Bs + (wn + j * 16 + fr) * LDSP + fq * 8);
#pragma unroll
        for (int i = 0; i < FI; ++i)
#pragma unroll
            for (int j = 0; j < FJ; ++j)
                acc[i][j] = __builtin_amdgcn_mfma_f32_16x16x32_bf16(af[i], bf[j], acc[i][j], 0, 0, 0);
        __syncthreads();
    }

    float*  Cf = p.Cf ? p.Cf + (long)h * p.cHead : (float*)0;
    bf16_t* Cb = p.Cb ? p.Cb + (long)h * p.cHead : (bf16_t*)0;
#pragma unroll
    for (int i = 0; i < FI; ++i) {
#pragma unroll
        for (int r = 0; r < 4; ++r) {
            const int m = m0 + wm + i * 16 + fq * 4 + r;
            if (m >= p.M) continue;
#pragma unroll
            for (int j = 0; j < FJ; ++j) {
                const int n = n0 + wn + j * 16 + fr;
                if (n >= p.N) continue;
                const float v = acc[i][j][r];
                const long idx = (long)m * p.ldc + n;
                if (p.atomicC)      atomicAdd(&Cf[idx], v);
                else if (Cf)        Cf[idx] = v;
                else                Cb[idx] = (bf16_t)v;
            }
        }
    }
}

// f32 [rows][257] -> bf16 [rows][288] zero-padded
__global__ void k_cast_pad(const float* __restrict__ in, bf16_t* __restrict__ out, long rows)
{
    long i = (long)blockIdx.x * 256 + threadIdx.x;
    if (i >= rows * KQP) return;
    long r = i / KQP; int k = (int)(i - r * KQP);
    out[i] = (k < KIN) ? (bf16_t)in[r * KIN + k] : (bf16_t)0.f;
}

// Wq/Wk/Wv [H][257][257] -> head-split padded [2176][288]
__global__ void k_prep_proj(const float* __restrict__ W, bf16_t* __restrict__ dst)
{
    long i = (long)blockIdx.x * 256 + threadIdx.x;
    if (i >= (long)DTOT * KQP) return;
    int r = (int)(i / KQP), k = (int)(i % KQP);
    float v = 0.f;
    if (r < SCOL) {
        int h = r >> 5, j = r & 31;
        if (j < SD && k < KIN) v = W[((long)h * 257 + j) * 257 + k];
    } else {
        int rr = r - SCOL;
        int h = rr / HD, j = rr % HD;
        if (k < KIN) v = W[((long)h * 257 + SD + j) * 257 + k];
    }
    dst[i] = (bf16_t)v;
}

// Ws [17][136] -> Wsb [17][256] head-split 32-padded
__global__ void k_prep_ws(const float* __restrict__ ws, bf16_t* __restrict__ out)
{
    int o = blockIdx.x; int t = threadIdx.x;
    int h = t >> 5, j = t & 31;
    out[o * 256 + t] = (j < SD) ? (bf16_t)ws[o * (H * SD) + h * SD + j] : (bf16_t)0.f;
}

// Wh [240][1920] -> Whb [240][2048] head-split 256-padded (v-cols)
__global__ void k_prep_wh(const float* __restrict__ wh, bf16_t* __restrict__ out)
{
    long i = (long)blockIdx.x * 256 + threadIdx.x;
    if (i >= 240L * 2048) return;
    int o = (int)(i / 2048), c = (int)(i % 2048);
    int h = c >> 8, j = c & 255;
    out[i] = (j < HD) ? (bf16_t)wh[(long)o * 1920 + h * HD + j] : (bf16_t)0.f;
}

// in-place post for fused KV row [K(2176) | V(2176)]
__global__ void __launch_bounds__(256)
k_post_kv(bf16_t* __restrict__ Ykv, int rows)
{
    const int wid  = blockIdx.x * 4 + (threadIdx.x >> 6);
    const int lane = threadIdx.x & 63;
    const int n = wid >> 3, h = wid & 7;
    if (n >= rows) return;
    bf16_t* row = Ykv + (long)n * (2 * DTOT);
    float kv = 0.f, vv = 0.f;
    if (lane < SD) {
        kv = (float)row[h * 32 + lane];
        vv = (float)row[DTOT + h * 32 + lane];
    }
    float sk = kv * kv, sv = vv * vv;
#pragma unroll
    for (int off = 32; off > 0; off >>= 1) {
        sk += __shfl_down(sk, off);
        sv += __shfl_down(sv, off);
    }
    sk = __shfl(sk, 0); sv = __shfl(sv, 0);
    const float ik = 1.f / (sqrtf(sk) + 1e-8f);
    const float iv = 1.f / (sqrtf(sv) + 1e-8f);
    if (lane < 32) {
        row[h * 32 + lane]        = (bf16_t)((lane < SD) ? phi_elu1(kv * ik) : 0.f);
        row[DTOT + h * 32 + lane] = (bf16_t)((lane < SD) ? vv * iv : 0.f);
    }
    for (int o = lane; o < HD; o += 64) {
        bf16_t* pk = row + SCOL + h * HD + o;
        *pk = (bf16_t)phi_elu1((float)*pk);
    }
}

// post for Q: phi + s-norm, compute den vs ksum, scale by 1/(den+eps) IN PLACE
__global__ void __launch_bounds__(256)
k_post_q(bf16_t* __restrict__ Yq, const float* __restrict__ ksum, int rows)
{
    const int wid  = blockIdx.x * 4 + (threadIdx.x >> 6);
    const int lane = threadIdx.x & 63;
    const int n = wid >> 3, h = wid & 7;
    if (n >= rows) return;
    bf16_t* row = Yq + (long)n * DTOT;
    float qv = (lane < SD) ? (float)row[h * 32 + lane] : 0.f;
    float sq = qv * qv;
#pragma unroll
    for (int off = 32; off > 0; off >>= 1) sq += __shfl_down(sq, off);
    sq = __shfl(sq, 0);
    const float iq = 1.f / (sqrtf(sq) + 1e-8f);
    float pvs = (lane < SD) ? phi_elu1(qv * iq) : 0.f;
    float ds = (lane < SD) ? pvs * ksum[h * 32 + lane] : 0.f;
    float pvh[4];
    float dh = 0.f;
#pragma unroll
    for (int i = 0; i < 4; ++i) {
        int o = lane + 64 * i;
        if (o < HD) {
            pvh[i] = phi_elu1((float)row[SCOL + h * HD + o]);
            dh += pvh[i] * ksum[SCOL + h * HD + o];
        } else pvh[i] = 0.f;
    }
#pragma unroll
    for (int off = 32; off > 0; off >>= 1) {
        ds += __shfl_down(ds, off);
        dh += __shfl_down(dh, off);
    }
    ds = __shfl(ds, 0); dh = __shfl(dh, 0);
    const float ss = 1.f / (ds + 1e-6f);
    const float sh = 1.f / (dh + 1e-8f);
    if (lane < 32)
        row[h * 32 + lane] = (bf16_t)((lane < SD) ? pvs * ss : 0.f);
#pragma unroll
    for (int i = 0; i < 4; ++i) {
        int o = lane + 64 * i;
        if (o < HD) row[SCOL + h * HD + o] = (bf16_t)(pvh[i] * sh);
    }
}

// column sums (atomic across row splits)
__global__ void k_colsum(const bf16_t* __restrict__ X, long lda, float* __restrict__ out,
                         int rows, int W)
{
    int col = blockIdx.x * 256 + threadIdx.x;
    if (col >= W) return;
    int per = (rows + gridDim.y - 1) / gridDim.y;
    int r0 = blockIdx.y * per;
    int r1 = r0 + per; if (r1 > rows) r1 = rows;
    float s = 0.f;
    for (int r = r0; r < r1; ++r) s += (float)X[(long)r * lda + col];
    atomicAdd(&out[col], s);
}

// transpose Ykv [R][4352] -> Tk[2176][chp], Tv[2176][chp]; zero-fill rows >= R
__global__ void __launch_bounds__(256)
k_transpose(const bf16_t* __restrict__ X, bf16_t* __restrict__ Tk, bf16_t* __restrict__ Tv,
            int R, int chp)
{
    const int t = threadIdx.x;
    const int c = t & 63;
    const int rchunk = t >> 6;
    const int r0 = blockIdx.x * 128;
    const int gcAll = blockIdx.y * 64 + c;
    bf16x8 w[4];
#pragma unroll
    for (int j = 0; j < 32; ++j) {
        const int gr = r0 + rchunk * 32 + j;
        float v = 0.f;
        if (gr < R) v = (float)X[(long)gr * (2 * DTOT) + gcAll];
        w[j >> 3][j & 7] = (bf16_t)v;
    }
    bf16_t* dstBase = (gcAll < DTOT) ? Tk : Tv;
    const int col = (gcAll < DTOT) ? gcAll : gcAll - DTOT;
    bf16_t* dst = dstBase + (long)col * chp + r0 + rchunk * 32;
#pragma unroll
    for (int q = 0; q < 4; ++q)
        *(bf16x8*)(dst + q * 8) = w[q];
}

// f32 -> bf16
__global__ void k_castf(const float* __restrict__ in, bf16_t* __restrict__ out, long n)
{
    long i = (long)blockIdx.x * 256 + threadIdx.x;
    if (i < n) out[i] = (bf16_t)in[i];
}

// final epilogue
__global__ void __launch_bounds__(256)
k_finalize(const float* __restrict__ pre, float* __restrict__ outp, int rows)
{
    int n    = blockIdx.x * 4 + (threadIdx.x >> 6);
    int lane = threadIdx.x & 63;
    if (n >= rows) return;
    const float* rp = pre + (long)n * 257;
    float* op = outp + (long)n * 257;
    float sv = (lane < SD) ? rp[lane] : 0.f;
    float ssq = sv * sv;
    float hv[4];
    float hsq = 0.f;
#pragma unroll
    for (int i = 0; i < 4; ++i) {
        int o = lane + 64 * i;
        hv[i] = (o < HD) ? rp[SD + o] : 0.f;
        hsq += hv[i] * hv[i];
    }
#pragma unroll
    for (int off = 32; off > 0; off >>= 1) {
        ssq += __shfl_down(ssq, off);
        hsq += __shfl_down(hsq, off);
    }
    ssq = __shfl(ssq, 0); hsq = __shfl(hsq, 0);
    float an_raw = sqrtf(ssq);
    float bn_raw = sqrtf(hsq);
    float an = an_raw + 1e-8f;
    float bn = bn_raw + 1e-8f;
    bool ma = an > 1e6f;
    bool mb = bn > 1e6f;
    float an_c = fminf(an, 1e6f);
    float bn_c = fminf(bn, 1e6f);
    float na = ma ? (an_raw / an_c) : an_raw;
    na = fmaxf(na, 1e-12f);
    float inv_s = (ma ? (1.f / an_c) : 1.f) / na;
    float bt = sqrtf(bn_c * bn_c + 1.0f);
    float nb = fmaxf(bn_raw / bn_c, 1e-12f);
    float scale_b = 1e6f / (bn_c * nb);
    if (lane < SD) op[lane] = bt * (sv * inv_s);
#pragma unroll
    for (int i = 0; i < 4; ++i) {
        int o = lane + 64 * i;
        if (o < HD) op[SD + o] = mb ? hv[i] * scale_b : hv[i];
    }
}

static inline long alup(long b) { return (b + 255) & ~255L; }

extern "C" void kernel_launch(void* const* d_in, const int* in_sizes, int n_in,
                              void* d_out, int out_size, void* d_ws, size_t ws_size,
                              hipStream_t stream)
{
    const float* query  = (const float*)d_in[0];
    const float* source = (const float*)d_in[1];
    const float* Wq     = (const float*)d_in[2];
    const float* Wk     = (const float*)d_in[3];
    const float* Wv     = (const float*)d_in[4];
    const float* Ws     = (const float*)d_in[5];
    const float* Wh     = (const float*)d_in[6];
    float* out = (float*)d_out;

    // ---- workspace (~119 MB) ----
    char* p = (char*)d_ws;
    auto alloc = [&](long b) { char* r = p; p += alup(b); return r; };
    bf16_t* Wkvb = (bf16_t*)alloc(2L * DTOT * KQP * 2);
    bf16_t* Wqb  = (bf16_t*)alloc((long)DTOT * KQP * 2);
    bf16_t* Wsb  = (bf16_t*)alloc(17L * 256 * 2);
    bf16_t* Whb  = (bf16_t*)alloc(240L * 2048 * 2);
    bf16_t* Gfull= (bf16_t*)alloc(257L * DTOT * 2);
    float*  ktvF = (float*) alloc((8L * HD * 256 + 8L * 32 * 32) * 4);   // [H][240][256] then [H][32][32]
    float*  ksum = (float*) alloc((long)DTOT * 4);                        // contiguous after ktvF
    bf16_t* ktvB = (bf16_t*)alloc((8L * HD * 256 + 8L * 32 * 32) * 2);
    bf16_t* Ykv  = (bf16_t*)alloc((long)CHS * 2 * DTOT * 2);              // [6000][4352]
    char* ub = alloc((long)CHQ * KQP * 2 + 2L * DTOT * CHPS * 2);         // union
    bf16_t* xcb = (bf16_t*)ub;                                            // [CHQ][288]
    bf16_t* Tk  = (bf16_t*)(ub + alup((long)CHQ * KQP * 2));              // [2176][6144]
    bf16_t* Tv  = Tk + (long)DTOT * CHPS;
    bf16_t* Yq  = Tk;                                                     // [7500][2176] (query phase)
    float*  opre= (float*)(Yq + (long)CHQ * DTOT);                        // [7500][257] f32

    float*  ktvHf = ktvF;
    float*  ktvSf = ktvF + 8L * HD * 256;
    bf16_t* ktvHb = ktvB;
    bf16_t* ktvSb = ktvB + 8L * HD * 256;

    (void)hipMemsetAsync(ktvF, 0, (char*)(ksum + DTOT) - (char*)ktvF, stream);
    (void)hipMemsetAsync(Gfull, 0, 257L * DTOT * 2, stream);

    // ---- weight prep ----
    const unsigned gw = (unsigned)(((long)DTOT * KQP + 255) / 256);
    k_prep_proj<<<gw, 256, 0, stream>>>(Wk, Wkvb);
    k_prep_proj<<<gw, 256, 0, stream>>>(Wv, Wkvb + (long)DTOT * KQP);
    k_prep_proj<<<gw, 256, 0, stream>>>(Wq, Wqb);
    k_prep_ws<<<17, 256, 0, stream>>>(Ws, Wsb);
    k_prep_wh<<<(unsigned)((240L * 2048 + 255) / 256), 256, 0, stream>>>(Wh, Whb);

    GemmP g;

    // ---------------- source phase ----------------
    for (int c = 0; c < NCS; ++c) {
        const float* src = source + (long)c * CHS * KIN;
        k_cast_pad<<<(unsigned)(((long)CHS * KQP + 255) / 256), 256, 0, stream>>>(src, xcb, CHS);
        // Ykv = xcb @ Wkvb^T
        g = { xcb, KQP, 0,  Wkvb, KQP, 0,  0, Ykv, 2 * DTOT, 0, 0,
              CHS, 2 * DTOT, KQP, 1 };
        k_mfma_nt<128, 128><<<dim3((CHS + 127) / 128, (2 * DTOT) / 128, 1), 256, 0, stream>>>(g);
        k_post_kv<<<(CHS * H) / 4, 256, 0, stream>>>(Ykv, CHS);
        k_colsum<<<dim3((DTOT + 255) / 256, 30), 256, 0, stream>>>(Ykv, 2 * DTOT, ksum, CHS, DTOT);
        k_transpose<<<dim3(CHPS / 128, (2 * DTOT) / 64), 256, 0, stream>>>(Ykv, Tk, Tv, CHS, CHPS);
        // ktvH_h[k'][v] += sum_n Tk_h[k'][n]*Tv_h[v][n]
        g = { Tk + (long)SCOL * CHPS, CHPS, (long)HD * CHPS,
              Tv + (long)SCOL * CHPS, CHPS, (long)HD * CHPS,
              ktvHf, 0, 256, (long)HD * 256, 1,  HD, HD, CHPS, KSPLIT };
        k_mfma_nt<128, 128><<<dim3(2, 2, H * KSPLIT), 256, 0, stream>>>(g);
        g = { Tk, CHPS, 32L * CHPS,  Tv, CHPS, 32L * CHPS,
              ktvSf, 0, 32, 32L * 32, 1,  32, 32, CHPS, KSPLIT };
        k_mfma_nt<64, 64><<<dim3(1, 1, H * KSPLIT), 256, 0, stream>>>(g);
    }
    k_castf<<<(unsigned)((8L * (HD * 256 + 32 * 32) + 255) / 256), 256, 0, stream>>>(
        ktvF, ktvB, 8L * (HD * 256 + 32 * 32));

    // ---- fold ktv into output weights: Gfull[o][k] ----
    // Gs: rows 0..16, cols h*32+k' : sum_v Ws_h[o][v]*ktvS_h[k'][v]
    g = { Wsb, 256, 32,  ktvSb, 32, 32L * 32,  0, Gfull, DTOT, 32, 0,
          SD, 32, 32, 1 };
    k_mfma_nt<64, 64><<<dim3(1, 1, H), 256, 0, stream>>>(g);
    // Gh: rows 17..256, cols 256+h*240+k' : sum_v Wh_h[o][v]*ktvH_h[k'][v]
    g = { Whb, 2048, 256,  ktvHb, 256, (long)HD * 256,
          0, Gfull + 17L * DTOT + SCOL, DTOT, HD, 0,
          HD, HD, 256, 1 };
    k_mfma_nt<64, 64><<<dim3(4, 4, H), 256, 0, stream>>>(g);

    // ---------------- query phase ----------------
    for (int c = 0; c < NCQ; ++c) {
        const float* qsrc = query + (long)c * CHQ * KIN;
        float* orow = out + (long)c * CHQ * 257;
        k_cast_pad<<<(unsigned)(((long)CHQ * KQP + 255) / 256), 256, 0, stream>>>(qsrc, xcb, CHQ);
        g = { xcb, KQP, 0,  Wqb, KQP, 0,  0, Yq, DTOT, 0, 0,
              CHQ, DTOT, KQP, 1 };
        k_mfma_nt<128, 128><<<dim3((CHQ + 127) / 128, DTOT / 128, 1), 256, 0, stream>>>(g);
        k_post_q<<<(CHQ * H) / 4, 256, 0, stream>>>(Yq, ksum, CHQ);
        // opre = Yq_scaled @ Gfull^T  (N=257, K=2176)
        g = { Yq, DTOT, 0,  Gfull, DTOT, 0,  opre, 0, 257, 0, 0,
              CHQ, 257, DTOT, 1 };
        k_mfma_nt<64, 64><<<dim3((CHQ + 63) / 64, 5, 1), 256, 0, stream>>>(g);
        k_finalize<<<(CHQ + 3) / 4, 256, 0, stream>>>(opre, orow, CHQ);
    }
}

// Round 6
// 1528.875 us; speedup vs baseline: 1.6814x; 1.1143x over previous
//
#include <hip/hip_runtime.h>
#include <math.h>

typedef __bf16 bf16_t;
typedef __bf16 bf16x8 __attribute__((ext_vector_type(8)));
typedef float f32x4 __attribute__((ext_vector_type(4)));

#define H    8
#define SD   17
#define HD   240
#define KIN  257
#define KQP  288      // padded K for projections
#define SCOL 256      // s-block width (8 x 32)
#define DTOT 2176     // 256 + 1920
#define NTOT 30000
#define CHS  6000     // source chunk
#define NCS  5
#define CHPS 6144     // CHS padded to 128
#define CHQ  7500     // query chunk
#define CHQP 7552     // CHQ padded to 128
#define NCQ  4
#define KSPLIT 16

#define BK   32       // LDS row stride = BK halves (NO pad: global_load_lds needs contiguous lane order)

__device__ __forceinline__ float phi_elu1(float x) {
    return x > 0.f ? x + 1.f : __expf(x);
}

// async 16B global -> LDS (DMA, no VGPR round-trip). dest must be wave-uniform base + lane*16.
__device__ __forceinline__ void gl_lds16(const bf16_t* g, bf16_t* l) {
    __builtin_amdgcn_global_load_lds(
        (const __attribute__((address_space(1))) void*)g,
        (__attribute__((address_space(3))) void*)l, 16, 0, 0);
}

struct GemmP {
    const bf16_t* A; long lda; long aHead;
    const bf16_t* B; long ldb; long bHead;
    float* Cf; bf16_t* Cb; long ldc; long cHead; int atomicC;
    int M, N, K, nSplit;
};

// C[m,n] = sum_k A[m,k]*B[n,k]; bf16 MFMA, f32 acc. K (per split) mult of 32.
// NOTE: no staging bounds checks — operand buffers MUST be allocated/padded to
// tile-multiple rows (garbage rows only feed discarded C rows/cols; K-pad cols zeroed).
template<int TBM, int TBN>
__global__ void __launch_bounds__(256)
k_mfma_nt(GemmP p)
{
    constexpr int FI = TBM / 32;
    constexpr int FJ = TBN / 32;
    __shared__ bf16_t As[TBM * BK];
    __shared__ bf16_t Bs[TBN * BK];
    const int t  = threadIdx.x;
    const int z  = blockIdx.z;
    const int h  = z / p.nSplit;
    const int sp = z % p.nSplit;
    const int kWin = p.K / p.nSplit;
    const int k0   = sp * kWin;
    const int m0 = blockIdx.x * TBM;
    const int n0 = blockIdx.y * TBN;
    const bf16_t* A = p.A + (long)h * p.aHead;
    const bf16_t* B = p.B + (long)h * p.bHead;

    const int lr = t >> 2;     // staging row within 64-group
    const int lc = t & 3;      // 16B chunk
    const int wid  = t >> 6;
    const int lane = t & 63;
    const int wm = (wid >> 1) * (TBM / 2);
    const int wn = (wid & 1) * (TBN / 2);
    const int fr = lane & 15;
    const int fq = lane >> 4;

    f32x4 acc[FI][FJ] = {};

    for (int kb = k0; kb < k0 + kWin; kb += BK) {
        const int gk = kb + lc * 8;
#pragma unroll
        for (int it = 0; it < TBM / 64; ++it)
            gl_lds16(A + (long)(m0 + lr + it * 64) * p.lda + gk, As + it * 2048 + t * 8);
#pragma unroll
        for (int it = 0; it < TBN / 64; ++it)
            gl_lds16(B + (long)(n0 + lr + it * 64) * p.ldb + gk, Bs + it * 2048 + t * 8);
        __syncthreads();
        bf16x8 af[FI], bf[FJ];
#pragma unroll
        for (int i = 0; i < FI; ++i)
            af[i] = *(const bf16x8*)(As + (wm + i * 16 + fr) * BK + fq * 8);
#pragma unroll
        for (int j = 0; j < FJ; ++j)
            bf[j] = *(const bf16x8*)(Bs + (wn + j * 16 + fr) * BK + fq * 8);
#pragma unroll
        for (int i = 0; i < FI; ++i)
#pragma unroll
            for (int j = 0; j < FJ; ++j)
                acc[i][j] = __builtin_amdgcn_mfma_f32_16x16x32_bf16(af[i], bf[j], acc[i][j], 0, 0, 0);
        __syncthreads();
    }

    float*  Cf = p.Cf ? p.Cf + (long)h * p.cHead : (float*)0;
    bf16_t* Cb = p.Cb ? p.Cb + (long)h * p.cHead : (bf16_t*)0;
#pragma unroll
    for (int i = 0; i < FI; ++i) {
#pragma unroll
        for (int r = 0; r < 4; ++r) {
            const int m = m0 + wm + i * 16 + fq * 4 + r;
            if (m >= p.M) continue;
#pragma unroll
            for (int j = 0; j < FJ; ++j) {
                const int n = n0 + wn + j * 16 + fr;
                if (n >= p.N) continue;
                const float v = acc[i][j][r];
                const long idx = (long)m * p.ldc + n;
                if (p.atomicC)      atomicAdd(&Cf[idx], v);
                else if (Cf)        Cf[idx] = v;
                else                Cb[idx] = (bf16_t)v;
            }
        }
    }
}

// f32 [rows][257] -> bf16 [rows][288] zero-padded
__global__ void k_cast_pad(const float* __restrict__ in, bf16_t* __restrict__ out, long rows)
{
    long i = (long)blockIdx.x * 256 + threadIdx.x;
    if (i >= rows * KQP) return;
    long r = i / KQP; int k = (int)(i - r * KQP);
    out[i] = (k < KIN) ? (bf16_t)in[r * KIN + k] : (bf16_t)0.f;
}

// Wq/Wk/Wv [H][257][257] -> head-split padded [2176][288]
__global__ void k_prep_proj(const float* __restrict__ W, bf16_t* __restrict__ dst)
{
    long i = (long)blockIdx.x * 256 + threadIdx.x;
    if (i >= (long)DTOT * KQP) return;
    int r = (int)(i / KQP), k = (int)(i % KQP);
    float v = 0.f;
    if (r < SCOL) {
        int h = r >> 5, j = r & 31;
        if (j < SD && k < KIN) v = W[((long)h * 257 + j) * 257 + k];
    } else {
        int rr = r - SCOL;
        int h = rr / HD, j = rr % HD;
        if (k < KIN) v = W[((long)h * 257 + SD + j) * 257 + k];
    }
    dst[i] = (bf16_t)v;
}

// Ws [17][136] -> Wsb [64][256] head-split 32-padded, zero rows >= 17
__global__ void k_prep_ws(const float* __restrict__ ws, bf16_t* __restrict__ out)
{
    int o = blockIdx.x; int t = threadIdx.x;
    int h = t >> 5, j = t & 31;
    float v = 0.f;
    if (o < SD && j < SD) v = ws[o * (H * SD) + h * SD + j];
    out[o * 256 + t] = (bf16_t)v;
}

// Wh [240][1920] -> Whb [256][2048] head-split 256-padded, zero rows >= 240
__global__ void k_prep_wh(const float* __restrict__ wh, bf16_t* __restrict__ out)
{
    long i = (long)blockIdx.x * 256 + threadIdx.x;
    if (i >= 256L * 2048) return;
    int o = (int)(i / 2048), c = (int)(i % 2048);
    int h = c >> 8, j = c & 255;
    float v = 0.f;
    if (o < 240 && j < HD) v = wh[(long)o * 1920 + h * HD + j];
    out[i] = (bf16_t)v;
}

// in-place post for fused KV row [K(2176) | V(2176)]
__global__ void __launch_bounds__(256)
k_post_kv(bf16_t* __restrict__ Ykv, int rows)
{
    const int wid  = blockIdx.x * 4 + (threadIdx.x >> 6);
    const int lane = threadIdx.x & 63;
    const int n = wid >> 3, h = wid & 7;
    if (n >= rows) return;
    bf16_t* row = Ykv + (long)n * (2 * DTOT);
    float kv = 0.f, vv = 0.f;
    if (lane < SD) {
        kv = (float)row[h * 32 + lane];
        vv = (float)row[DTOT + h * 32 + lane];
    }
    float sk = kv * kv, sv = vv * vv;
#pragma unroll
    for (int off = 32; off > 0; off >>= 1) {
        sk += __shfl_down(sk, off);
        sv += __shfl_down(sv, off);
    }
    sk = __shfl(sk, 0); sv = __shfl(sv, 0);
    const float ik = 1.f / (sqrtf(sk) + 1e-8f);
    const float iv = 1.f / (sqrtf(sv) + 1e-8f);
    if (lane < 32) {
        row[h * 32 + lane]        = (bf16_t)((lane < SD) ? phi_elu1(kv * ik) : 0.f);
        row[DTOT + h * 32 + lane] = (bf16_t)((lane < SD) ? vv * iv : 0.f);
    }
    for (int o = lane; o < HD; o += 64) {
        bf16_t* pk = row + SCOL + h * HD + o;
        *pk = (bf16_t)phi_elu1((float)*pk);
    }
}

// post for Q: phi + s-norm, compute den vs ksum, scale by 1/(den+eps) IN PLACE
__global__ void __launch_bounds__(256)
k_post_q(bf16_t* __restrict__ Yq, const float* __restrict__ ksum, int rows)
{
    const int wid  = blockIdx.x * 4 + (threadIdx.x >> 6);
    const int lane = threadIdx.x & 63;
    const int n = wid >> 3, h = wid & 7;
    if (n >= rows) return;
    bf16_t* row = Yq + (long)n * DTOT;
    float qv = (lane < SD) ? (float)row[h * 32 + lane] : 0.f;
    float sq = qv * qv;
#pragma unroll
    for (int off = 32; off > 0; off >>= 1) sq += __shfl_down(sq, off);
    sq = __shfl(sq, 0);
    const float iq = 1.f / (sqrtf(sq) + 1e-8f);
    float pvs = (lane < SD) ? phi_elu1(qv * iq) : 0.f;
    float ds = (lane < SD) ? pvs * ksum[h * 32 + lane] : 0.f;
    float pvh[4];
    float dh = 0.f;
#pragma unroll
    for (int i = 0; i < 4; ++i) {
        int o = lane + 64 * i;
        if (o < HD) {
            pvh[i] = phi_elu1((float)row[SCOL + h * HD + o]);
            dh += pvh[i] * ksum[SCOL + h * HD + o];
        } else pvh[i] = 0.f;
    }
#pragma unroll
    for (int off = 32; off > 0; off >>= 1) {
        ds += __shfl_down(ds, off);
        dh += __shfl_down(dh, off);
    }
    ds = __shfl(ds, 0); dh = __shfl(dh, 0);
    const float ss = 1.f / (ds + 1e-6f);
    const float sh = 1.f / (dh + 1e-8f);
    if (lane < 32)
        row[h * 32 + lane] = (bf16_t)((lane < SD) ? pvs * ss : 0.f);
#pragma unroll
    for (int i = 0; i < 4; ++i) {
        int o = lane + 64 * i;
        if (o < HD) row[SCOL + h * HD + o] = (bf16_t)(pvh[i] * sh);
    }
}

// column sums (atomic across row splits)
__global__ void k_colsum(const bf16_t* __restrict__ X, long lda, float* __restrict__ out,
                         int rows, int W)
{
    int col = blockIdx.x * 256 + threadIdx.x;
    if (col >= W) return;
    int per = (rows + gridDim.y - 1) / gridDim.y;
    int r0 = blockIdx.y * per;
    int r1 = r0 + per; if (r1 > rows) r1 = rows;
    float s = 0.f;
    for (int r = r0; r < r1; ++r) s += (float)X[(long)r * lda + col];
    atomicAdd(&out[col], s);
}

// transpose Ykv [R][4352] -> Tk[2176][chp], Tv[2176][chp]; zero-fill rows >= R
__global__ void __launch_bounds__(256)
k_transpose(const bf16_t* __restrict__ X, bf16_t* __restrict__ Tk, bf16_t* __restrict__ Tv,
            int R, int chp)
{
    const int t = threadIdx.x;
    const int c = t & 63;
    const int rchunk = t >> 6;
    const int r0 = blockIdx.x * 128;
    const int gcAll = blockIdx.y * 64 + c;
    bf16x8 w[4];
#pragma unroll
    for (int j = 0; j < 32; ++j) {
        const int gr = r0 + rchunk * 32 + j;
        float v = 0.f;
        if (gr < R) v = (float)X[(long)gr * (2 * DTOT) + gcAll];
        w[j >> 3][j & 7] = (bf16_t)v;
    }
    bf16_t* dstBase = (gcAll < DTOT) ? Tk : Tv;
    const int col = (gcAll < DTOT) ? gcAll : gcAll - DTOT;
    bf16_t* dst = dstBase + (long)col * chp + r0 + rchunk * 32;
#pragma unroll
    for (int q = 0; q < 4; ++q)
        *(bf16x8*)(dst + q * 8) = w[q];
}

// f32 -> bf16
__global__ void k_castf(const float* __restrict__ in, bf16_t* __restrict__ out, long n)
{
    long i = (long)blockIdx.x * 256 + threadIdx.x;
    if (i < n) out[i] = (bf16_t)in[i];
}

// final epilogue
__global__ void __launch_bounds__(256)
k_finalize(const float* __restrict__ pre, float* __restrict__ outp, int rows)
{
    int n    = blockIdx.x * 4 + (threadIdx.x >> 6);
    int lane = threadIdx.x & 63;
    if (n >= rows) return;
    const float* rp = pre + (long)n * 257;
    float* op = outp + (long)n * 257;
    float sv = (lane < SD) ? rp[lane] : 0.f;
    float ssq = sv * sv;
    float hv[4];
    float hsq = 0.f;
#pragma unroll
    for (int i = 0; i < 4; ++i) {
        int o = lane + 64 * i;
        hv[i] = (o < HD) ? rp[SD + o] : 0.f;
        hsq += hv[i] * hv[i];
    }
#pragma unroll
    for (int off = 32; off > 0; off >>= 1) {
        ssq += __shfl_down(ssq, off);
        hsq += __shfl_down(hsq, off);
    }
    ssq = __shfl(ssq, 0); hsq = __shfl(hsq, 0);
    float an_raw = sqrtf(ssq);
    float bn_raw = sqrtf(hsq);
    float an = an_raw + 1e-8f;
    float bn = bn_raw + 1e-8f;
    bool ma = an > 1e6f;
    bool mb = bn > 1e6f;
    float an_c = fminf(an, 1e6f);
    float bn_c = fminf(bn, 1e6f);
    float na = ma ? (an_raw / an_c) : an_raw;
    na = fmaxf(na, 1e-12f);
    float inv_s = (ma ? (1.f / an_c) : 1.f) / na;
    float bt = sqrtf(bn_c * bn_c + 1.0f);
    float nb = fmaxf(bn_raw / bn_c, 1e-12f);
    float scale_b = 1e6f / (bn_c * nb);
    if (lane < SD) op[lane] = bt * (sv * inv_s);
#pragma unroll
    for (int i = 0; i < 4; ++i) {
        int o = lane + 64 * i;
        if (o < HD) op[SD + o] = mb ? hv[i] * scale_b : hv[i];
    }
}

static inline long alup(long b) { return (b + 255) & ~255L; }

extern "C" void kernel_launch(void* const* d_in, const int* in_sizes, int n_in,
                              void* d_out, int out_size, void* d_ws, size_t ws_size,
                              hipStream_t stream)
{
    const float* query  = (const float*)d_in[0];
    const float* source = (const float*)d_in[1];
    const float* Wq     = (const float*)d_in[2];
    const float* Wk     = (const float*)d_in[3];
    const float* Wv     = (const float*)d_in[4];
    const float* Ws     = (const float*)d_in[5];
    const float* Wh     = (const float*)d_in[6];
    float* out = (float*)d_out;

    // ---- workspace (~121 MB; proven ws >= ~205 MB). All GEMM operands padded to
    // tile-multiple rows because async staging has no bounds checks. ----
    char* p = (char*)d_ws;
    auto alloc = [&](long b) { char* r = p; p += alup(b); return r; };
    bf16_t* Wkvb = (bf16_t*)alloc(2L * DTOT * KQP * 2);       // [4352][288]
    bf16_t* Wqb  = (bf16_t*)alloc((long)DTOT * KQP * 2);      // [2176][288]
    bf16_t* Wsb  = (bf16_t*)alloc(64L * 256 * 2);             // [64][256] zero-padded
    bf16_t* Whb  = (bf16_t*)alloc(256L * 2048 * 2);           // [256][2048] zero-padded
    bf16_t* Gfull= (bf16_t*)alloc(320L * DTOT * 2);           // [320][2176] zeroed
    float*  ktvF = (float*) alloc((8L * HD * 256 + 8L * 32 * 32) * 4);
    float*  ksum = (float*) alloc((long)DTOT * 4);            // contiguous after ktvF
    bf16_t* ktvB = (bf16_t*)alloc((8L * HD * 256 + 8L * 32 * 32) * 2);
    bf16_t* xcb  = (bf16_t*)alloc((long)CHQP * KQP * 2);      // [7552][288]
    bf16_t* Ykv  = (bf16_t*)alloc((long)CHS * 2 * DTOT * 2);  // [6000][4352]
    // union: source {Tk,Tv(+16 slack rows)} / query {Yq(7552 rows), opre}
    long tkBytes = (long)DTOT * CHPS * 2;
    char* ub = alloc(2 * tkBytes + 16L * CHPS * 2);
    bf16_t* Tk  = (bf16_t*)ub;
    bf16_t* Tv  = Tk + (long)DTOT * CHPS;
    bf16_t* Yq  = Tk;                                         // [7552][2176]
    float*  opre= (float*)(Yq + (long)CHQP * DTOT);           // [7500][257] f32

    float*  ktvHf = ktvF;
    float*  ktvSf = ktvF + 8L * HD * 256;
    bf16_t* ktvHb = ktvB;
    bf16_t* ktvSb = ktvB + 8L * HD * 256;

    (void)hipMemsetAsync(ktvF, 0, (char*)(ksum + DTOT) - (char*)ktvF, stream);
    (void)hipMemsetAsync(Gfull, 0, 320L * DTOT * 2, stream);

    // ---- weight prep ----
    const unsigned gw = (unsigned)(((long)DTOT * KQP + 255) / 256);
    k_prep_proj<<<gw, 256, 0, stream>>>(Wk, Wkvb);
    k_prep_proj<<<gw, 256, 0, stream>>>(Wv, Wkvb + (long)DTOT * KQP);
    k_prep_proj<<<gw, 256, 0, stream>>>(Wq, Wqb);
    k_prep_ws<<<64, 256, 0, stream>>>(Ws, Wsb);
    k_prep_wh<<<(unsigned)((256L * 2048 + 255) / 256), 256, 0, stream>>>(Wh, Whb);

    GemmP g;

    // ---------------- source phase ----------------
    for (int c = 0; c < NCS; ++c) {
        const float* src = source + (long)c * CHS * KIN;
        k_cast_pad<<<(unsigned)(((long)CHS * KQP + 255) / 256), 256, 0, stream>>>(src, xcb, CHS);
        // Ykv = xcb @ Wkvb^T
        g = { xcb, KQP, 0,  Wkvb, KQP, 0,  0, Ykv, 2 * DTOT, 0, 0,
              CHS, 2 * DTOT, KQP, 1 };
        k_mfma_nt<128, 128><<<dim3((CHS + 127) / 128, (2 * DTOT) / 128, 1), 256, 0, stream>>>(g);
        k_post_kv<<<(CHS * H) / 4, 256, 0, stream>>>(Ykv, CHS);
        k_colsum<<<dim3((DTOT + 255) / 256, 30), 256, 0, stream>>>(Ykv, 2 * DTOT, ksum, CHS, DTOT);
        k_transpose<<<dim3(CHPS / 128, (2 * DTOT) / 64), 256, 0, stream>>>(Ykv, Tk, Tv, CHS, CHPS);
        // ktvH_h[k'][v] += sum_n Tk_h[k'][n]*Tv_h[v][n]
        g = { Tk + (long)SCOL * CHPS, CHPS, (long)HD * CHPS,
              Tv + (long)SCOL * CHPS, CHPS, (long)HD * CHPS,
              ktvHf, 0, 256, (long)HD * 256, 1,  HD, HD, CHPS, KSPLIT };
        k_mfma_nt<128, 128><<<dim3(2, 2, H * KSPLIT), 256, 0, stream>>>(g);
        g = { Tk, CHPS, 32L * CHPS,  Tv, CHPS, 32L * CHPS,
              ktvSf, 0, 32, 32L * 32, 1,  32, 32, CHPS, KSPLIT };
        k_mfma_nt<64, 64><<<dim3(1, 1, H * KSPLIT), 256, 0, stream>>>(g);
    }
    k_castf<<<(unsigned)((8L * (HD * 256 + 32 * 32) + 255) / 256), 256, 0, stream>>>(
        ktvF, ktvB, 8L * (HD * 256 + 32 * 32));

    // ---- fold ktv into output weights: Gfull[o][k] ----
    g = { Wsb, 256, 32,  ktvSb, 32, 32L * 32,  0, Gfull, DTOT, 32, 0,
          SD, 32, 32, 1 };
    k_mfma_nt<64, 64><<<dim3(1, 1, H), 256, 0, stream>>>(g);
    g = { Whb, 2048, 256,  ktvHb, 256, (long)HD * 256,
          0, Gfull + 17L * DTOT + SCOL, DTOT, HD, 0,
          HD, HD, 256, 1 };
    k_mfma_nt<64, 64><<<dim3(4, 4, H), 256, 0, stream>>>(g);

    // ---------------- query phase ----------------
    for (int c = 0; c < NCQ; ++c) {
        const float* qsrc = query + (long)c * CHQ * KIN;
        float* orow = out + (long)c * CHQ * 257;
        k_cast_pad<<<(unsigned)(((long)CHQ * KQP + 255) / 256), 256, 0, stream>>>(qsrc, xcb, CHQ);
        g = { xcb, KQP, 0,  Wqb, KQP, 0,  0, Yq, DTOT, 0, 0,
              CHQ, DTOT, KQP, 1 };
        k_mfma_nt<128, 128><<<dim3((CHQ + 127) / 128, DTOT / 128, 1), 256, 0, stream>>>(g);
        k_post_q<<<(CHQ * H) / 4, 256, 0, stream>>>(Yq, ksum, CHQ);
        // opre = Yq_scaled @ Gfull^T  (N=257, K=2176)
        g = { Yq, DTOT, 0,  Gfull, DTOT, 0,  opre, 0, 257, 0, 0,
              CHQ, 257, DTOT, 1 };
        k_mfma_nt<64, 64><<<dim3((CHQ + 63) / 64, 5, 1), 256, 0, stream>>>(g);
        k_finalize<<<(CHQ + 3) / 4, 256, 0, stream>>>(opre, orow, CHQ);
    }
}